// Round 1
// baseline (940.397 us; speedup 1.0000x reference)
//
#include <hip/hip_runtime.h>
#include <math.h>

#define NB 64
#define NP 16320
#define NO 24
#define NC 81

// ---------------------------------------------------------------------------
// Workspace layout (bytes):
//   [0,           12288)   best_key  : u64[NB*NO]   (zeroed each launch)
//   [12288,       12544)   npos      : int[NB]      (zeroed)
//   [12544,       12560)   acc       : float[4]     (zeroed) 0=loss_l 1=ce_pos 2=ce_neg
//   [12800,       ...  )   bto       : float[NB*NP]
//   next                   bti       : int  [NB*NP]
//   next                   ce_mine   : float[NB*NP]
// ---------------------------------------------------------------------------

__device__ __forceinline__ float smooth_l1(float d) {
    float a = fabsf(d);
    return (a < 1.0f) ? 0.5f * a * a : a - 0.5f;
}

// Kernel 1: decode ARM boxes, IoU vs truths, per-prior best (bto/bti),
// per-truth best prior. v2: each thread owns 4 priors (block = 1024 priors)
// so the per-object cross-lane reduction runs on 4x fewer waves and uses a
// single packed u64 key (iou_bits<<32 | ~p; ties -> smallest p).
__global__ __launch_bounds__(256) void k_match(
    const float* __restrict__ arm_loc, const float* __restrict__ priors,
    const float* __restrict__ gt_boxes,
    float* __restrict__ bto, int* __restrict__ bti,
    unsigned long long* __restrict__ best_key)
{
    const int b     = blockIdx.y;
    const int tid   = threadIdx.x;
    const int pbase = blockIdx.x * 1024;

    __shared__ float tr[NO * 4];
    __shared__ unsigned long long sh_best[NO];
    if (tid < NO * 4) tr[tid] = gt_boxes[b * NO * 4 + tid];
    if (tid < NO)     sh_best[tid] = 0ULL;
    __syncthreads();

    float x0[4], y0[4], x1[4], y1[4], ab[4];
    bool  val[4];
    #pragma unroll
    for (int c = 0; c < 4; ++c) {
        const int p = pbase + c * 256 + tid;
        val[c] = (p < NP);
        const int pc = val[c] ? p : 0;
        const float4 l  = ((const float4*)arm_loc)[(size_t)b * NP + pc];
        const float4 pr = ((const float4*)priors)[pc];
        const float cx = pr.x + l.x * 0.1f * pr.z;
        const float cy = pr.y + l.y * 0.1f * pr.w;
        const float wx = pr.z * expf(l.z * 0.2f);
        const float wy = pr.w * expf(l.w * 0.2f);
        x0[c] = cx - wx * 0.5f; y0[c] = cy - wy * 0.5f;
        x1[c] = cx + wx * 0.5f; y1[c] = cy + wy * 0.5f;
        ab[c] = (x1[c] - x0[c]) * (y1[c] - y0[c]);
    }

    float best[4]  = {-1.0f, -1.0f, -1.0f, -1.0f};
    int   besto[4] = {0, 0, 0, 0};

    for (int o = 0; o < NO; ++o) {
        const float tx0 = tr[o * 4 + 0], ty0 = tr[o * 4 + 1];
        const float tx1 = tr[o * 4 + 2], ty1 = tr[o * 4 + 3];
        const float aa  = (tx1 - tx0) * (ty1 - ty0);

        unsigned long long key = 0ULL;
        #pragma unroll
        for (int c = 0; c < 4; ++c) {
            const float iw = fmaxf(fminf(tx1, x1[c]) - fmaxf(tx0, x0[c]), 0.0f);
            const float ih = fmaxf(fminf(ty1, y1[c]) - fmaxf(ty0, y0[c]), 0.0f);
            const float inter = iw * ih;
            const float iou = inter / (aa + ab[c] - inter);
            if (iou > best[c]) { best[c] = iou; besto[c] = o; }  // first occurrence
            const int p = pbase + c * 256 + tid;
            const unsigned long long kc =
                ((unsigned long long)__float_as_uint(iou) << 32) | (unsigned)~(unsigned)p;
            if (val[c] && kc > key) key = kc;
        }
        // 64-lane max of packed key
        #pragma unroll
        for (int d = 1; d < 64; d <<= 1) {
            const unsigned long long k2 = __shfl_xor(key, d, 64);
            if (k2 > key) key = k2;
        }
        if ((tid & 63) == 0) atomicMax(&sh_best[o], key);
    }

    #pragma unroll
    for (int c = 0; c < 4; ++c) {
        if (val[c]) {
            const size_t idx = (size_t)b * NP + (pbase + c * 256 + tid);
            bto[idx] = best[c];
            bti[idx] = besto[c];
        }
    }
    __syncthreads();
    if (tid < NO) atomicMax(&best_key[b * NO + tid], sh_best[tid]);
}

// Kernel 2: force-match best prior per truth (last write wins = np scatter).
__global__ void k_force(const unsigned long long* __restrict__ best_key,
                        float* __restrict__ bto, int* __restrict__ bti)
{
    const int b = blockIdx.x * blockDim.x + threadIdx.x;
    if (b >= NB) return;
    for (int o = 0; o < NO; ++o) {
        const unsigned long long k = best_key[b * NO + o];
        const unsigned p = ~(unsigned)(k & 0xffffffffULL);
        bto[(size_t)b * NP + p] = 2.0f;
        bti[(size_t)b * NP + p] = o;
    }
}

// Kernel 3: LDS-staged coalesced CE + SmoothL1.
// v2: two-pass register-cached logsumexp (branch-free max, independent
// __expf into 4 accumulators -- no serial rescale chain, no divergence),
// target logit gathered with one LDS read, and register-prefetch of the
// next phase's staging loads so HBM latency hides under compute.
__global__ __launch_bounds__(256) void k_loss(
    const float* __restrict__ arm_loc, const float* __restrict__ arm_conf,
    const float* __restrict__ odm_loc, const float* __restrict__ odm_conf,
    const float* __restrict__ priors,  const float* __restrict__ gt_boxes,
    const int*   __restrict__ gt_labels,
    const float* __restrict__ bto, const int* __restrict__ bti,
    float* __restrict__ ce_mine, int* __restrict__ npos, float* __restrict__ acc)
{
    const int tid = threadIdx.x;
    const size_t rbase = (size_t)blockIdx.x * 256;

    __shared__ float4 stage4[(64 * NC + 3) / 4];       // 5184 floats = 1296 float4
    __shared__ float  ce_sh[256];
    __shared__ int    conf_sh[256];
    float* stage = (float*)stage4;

    // Prologue: issue phase-0 staging loads early.
    float4 pre[6];
    {
        const float4* src4 = (const float4*)(odm_conf + rbase * NC);
        #pragma unroll
        for (int k = 0; k < 6; ++k) {
            const int i = tid + 256 * k;
            if (i < 1296) pre[k] = src4[i];
        }
    }

    // Per-row target class.
    {
        const size_t row = rbase + tid;
        const int   bb = (int)(row / NP);
        const float ov = bto[row];
        const int   ti = bti[row];
        int ct = 0;
        if (!(ov < 0.5f)) ct = gt_labels[bb * NO + ti];
        conf_sh[tid] = ct;
    }

    for (int s = 0; s < 4; ++s) {
        // Write staged registers to LDS.
        #pragma unroll
        for (int k = 0; k < 6; ++k) {
            const int i = tid + 256 * k;
            if (i < 1296) stage4[i] = pre[k];
        }
        __syncthreads();

        // Issue next phase's loads under this phase's compute.
        if (s < 3) {
            const float4* src4 = (const float4*)(odm_conf + (rbase + 64 * (size_t)(s + 1)) * NC);
            #pragma unroll
            for (int k = 0; k < 6; ++k) {
                const int i = tid + 256 * k;
                if (i < 1296) pre[k] = src4[i];
            }
        }

        const int lr  = tid >> 2;          // local row 0..63
        const int q   = tid & 3;           // quarter 0..3
        const int tgt = conf_sh[64 * s + lr];
        const int j0  = q * 21;            // q<3: 21 elems; q==3: 18 valid
        const float* rowp = stage + lr * NC;

        // Load this thread's slice into registers (masked tail for q==3).
        float x[21];
        #pragma unroll
        for (int jj = 0; jj < 21; ++jj) {
            const int j = j0 + jj;
            const float v = rowp[(j < NC) ? j : (NC - 1)];
            x[jj] = (j < NC) ? v : -INFINITY;
        }

        // Pass 1: branch-free max, then 4-lane butterfly.
        float m = x[0];
        #pragma unroll
        for (int jj = 1; jj < 21; ++jj) m = fmaxf(m, x[jj]);
        #pragma unroll
        for (int d = 1; d < 4; d <<= 1) m = fmaxf(m, __shfl_xor(m, d, 64));

        // Gather target logit with one LDS read (same for all 4 lanes of row).
        const float gv = rowp[tgt];

        // Pass 2: independent exps, 4 accumulators to break the add chain.
        float a0 = 0.0f, a1 = 0.0f, a2 = 0.0f, a3 = 0.0f;
        #pragma unroll
        for (int jj = 0; jj < 21; jj += 4) {
            a0 += __expf(x[jj] - m);
            if (jj + 1 < 21) a1 += __expf(x[jj + 1] - m);
            if (jj + 2 < 21) a2 += __expf(x[jj + 2] - m);
            if (jj + 3 < 21) a3 += __expf(x[jj + 3] - m);
        }
        float sum = (a0 + a1) + (a2 + a3);
        #pragma unroll
        for (int d = 1; d < 4; d <<= 1) sum += __shfl_xor(sum, d, 64);

        if (q == 0) ce_sh[64 * s + lr] = (m + logf(sum)) - gv;
        __syncthreads();   // all reads of stage done before next phase's write
    }

    // Epilogue: per-thread row work (ocml-accurate math on threshold paths).
    float local_l = 0.0f, local_ce = 0.0f;
    int   local_n = 0;
    {
        const size_t row = rbase + tid;
        const int bb = (int)(row / NP);
        const int p  = (int)(row - (size_t)bb * NP);
        const int ct = conf_sh[tid];
        const float ce = ce_sh[tid];

        const float2 c = ((const float2*)arm_conf)[row];
        const float mm = fmaxf(c.x, c.y);
        const float e0 = expf(c.x - mm), e1 = expf(c.y - mm);
        const float score = e1 / (e0 + e1);
        const bool pos = (ct > 0) && (score > 0.01f);

        float cem = ce;
        if (pos) {
            cem      = 0.0f;
            local_ce = ce;
            local_n  = 1;
            const float4 l  = ((const float4*)arm_loc)[row];
            const float4 pr = ((const float4*)priors)[p];
            const float cx = pr.x + l.x * 0.1f * pr.z;
            const float cy = pr.y + l.y * 0.1f * pr.w;
            const float wx = pr.z * expf(l.z * 0.2f);
            const float wy = pr.w * expf(l.w * 0.2f);
            const float x0 = cx - wx * 0.5f, y0 = cy - wy * 0.5f;
            const float x1 = cx + wx * 0.5f, y1 = cy + wy * 0.5f;
            const float csx = (x0 + x1) * 0.5f, csy = (y0 + y1) * 0.5f;
            const float csw = x1 - x0,          csh = y1 - y0;
            const int ti = bti[row];
            const float4 mt = ((const float4*)gt_boxes)[bb * NO + ti];
            const float t0 = ((mt.x + mt.z) * 0.5f - csx) / (0.1f * csw);
            const float t1 = ((mt.y + mt.w) * 0.5f - csy) / (0.1f * csh);
            const float t2 = logf((mt.z - mt.x) / csw) / 0.2f;
            const float t3 = logf((mt.w - mt.y) / csh) / 0.2f;
            const float4 ol = ((const float4*)odm_loc)[row];
            local_l += smooth_l1(ol.x - t0);
            local_l += smooth_l1(ol.y - t1);
            local_l += smooth_l1(ol.z - t2);
            local_l += smooth_l1(ol.w - t3);
        }
        ce_mine[row] = cem;
    }

    // Block reduction (reuse stage LDS; protected by the final phase sync).
    float* sl = stage;
    float* sc = stage + 256;
    int*   sn = (int*)(stage + 512);
    sl[tid] = local_l; sc[tid] = local_ce; sn[tid] = local_n;
    __syncthreads();
    for (int st = 128; st > 0; st >>= 1) {
        if (tid < st) {
            sl[tid] += sl[tid + st];
            sc[tid] += sc[tid + st];
            sn[tid] += sn[tid + st];
        }
        __syncthreads();
    }
    if (tid == 0) {
        if (sl[0] != 0.0f) atomicAdd(&acc[0], sl[0]);
        if (sc[0] != 0.0f) atomicAdd(&acc[1], sc[0]);
    }
    // npos is per-batch; a block can span a batch boundary -> per-thread atomic
    // (only positives pay it; npos is small).
    {
        const size_t row = rbase + tid;
        const int bb = (int)(row / NP);
        if (local_n) atomicAdd(&npos[bb], 1);
    }
}

// Kernel 4: per-row radix select of k-th largest ce_mine.
// v2: per-wave privatized histograms (padded stride 257 to decouple banks)
// and a parallel suffix-scan instead of the serial 256-bin walk.
__global__ __launch_bounds__(256) void k_select(
    const float* __restrict__ ce_mine, const int* __restrict__ npos,
    float* __restrict__ acc)
{
    const int b   = blockIdx.x;
    const int tid = threadIdx.x;
    const int np  = npos[b];
    int k = 3 * np;
    if (k > NP - 1) k = NP - 1;
    if (k <= 0) return;

    const float4* row4 = (const float4*)(ce_mine + (size_t)b * NP);  // 4080 float4
    const int w = tid >> 6;

    __shared__ unsigned int hist[4][257];   // +1 pad: wave w starts at bank w
    __shared__ unsigned int scan[256];
    __shared__ unsigned int sh_prefix, sh_mask, sh_krem;
    if (tid == 0) { sh_prefix = 0u; sh_mask = 0u; sh_krem = (unsigned)k; }
    __syncthreads();

    for (int pass = 3; pass >= 0; --pass) {
        const unsigned mask   = sh_mask;
        const unsigned prefix = sh_prefix;
        const unsigned krem   = sh_krem;
        const int shift = pass * 8;

        hist[0][tid] = 0u; hist[1][tid] = 0u; hist[2][tid] = 0u; hist[3][tid] = 0u;
        __syncthreads();

        for (int i = tid; i < 4080; i += 256) {
            const float4 v = row4[i];
            const unsigned u0 = __float_as_uint(v.x);
            const unsigned u1 = __float_as_uint(v.y);
            const unsigned u2 = __float_as_uint(v.z);
            const unsigned u3 = __float_as_uint(v.w);
            if ((u0 & mask) == prefix) atomicAdd(&hist[w][(u0 >> shift) & 255u], 1u);
            if ((u1 & mask) == prefix) atomicAdd(&hist[w][(u1 >> shift) & 255u], 1u);
            if ((u2 & mask) == prefix) atomicAdd(&hist[w][(u2 >> shift) & 255u], 1u);
            if ((u3 & mask) == prefix) atomicAdd(&hist[w][(u3 >> shift) & 255u], 1u);
        }
        __syncthreads();

        const unsigned h = hist[0][tid] + hist[1][tid] + hist[2][tid] + hist[3][tid];
        scan[tid] = h;
        __syncthreads();
        // suffix-inclusive scan: scan[t] = sum_{j>=t} h[j]
        for (int off = 1; off < 256; off <<= 1) {
            const unsigned v = (tid + off < 256) ? scan[tid + off] : 0u;
            __syncthreads();
            scan[tid] += v;
            __syncthreads();
        }
        const unsigned sfx = scan[tid];
        if (sfx >= krem && (sfx - h) < krem) {   // unique threshold bin
            sh_prefix = prefix | ((unsigned)tid << shift);
            sh_mask   = mask | (255u << shift);
            sh_krem   = krem - (sfx - h);
        }
        __syncthreads();
    }

    const unsigned T = sh_prefix;   // exact bits of k-th largest
    float    lsum = 0.0f;
    unsigned lcnt = 0;
    for (int i = tid; i < 4080; i += 256) {
        const float4 v = row4[i];
        if (__float_as_uint(v.x) > T) { lsum += v.x; lcnt++; }
        if (__float_as_uint(v.y) > T) { lsum += v.y; lcnt++; }
        if (__float_as_uint(v.z) > T) { lsum += v.z; lcnt++; }
        if (__float_as_uint(v.w) > T) { lsum += v.w; lcnt++; }
    }
    __shared__ float    ssum[256];
    __shared__ unsigned scnt[256];
    ssum[tid] = lsum; scnt[tid] = lcnt;
    __syncthreads();
    for (int st = 128; st > 0; st >>= 1) {
        if (tid < st) { ssum[tid] += ssum[tid + st]; scnt[tid] += scnt[tid + st]; }
        __syncthreads();
    }
    if (tid == 0) {
        const float tf = __uint_as_float(T);
        const float contrib = ssum[0] + (float)(k - (int)scnt[0]) * tf;
        atomicAdd(&acc[2], contrib);
    }
}

// Kernel 5: finalize
__global__ void k_final(const float* __restrict__ acc, const int* __restrict__ npos,
                        float* __restrict__ out)
{
    if (threadIdx.x == 0 && blockIdx.x == 0) {
        int n = 0;
        for (int b = 0; b < NB; ++b) n += npos[b];
        const float N = (float)n;
        out[0] = acc[0] / N;
        out[1] = (acc[1] + acc[2]) / N;
    }
}

extern "C" void kernel_launch(void* const* d_in, const int* in_sizes, int n_in,
                              void* d_out, int out_size, void* d_ws, size_t ws_size,
                              hipStream_t stream)
{
    const float* arm_loc   = (const float*)d_in[0];
    const float* arm_conf  = (const float*)d_in[1];
    const float* odm_loc   = (const float*)d_in[2];
    const float* odm_conf  = (const float*)d_in[3];
    const float* priors    = (const float*)d_in[4];
    const float* gt_boxes  = (const float*)d_in[5];
    const int*   gt_labels = (const int*)d_in[6];
    float* out = (float*)d_out;

    char* ws = (char*)d_ws;
    unsigned long long* best_key = (unsigned long long*)ws;          // 12288 B
    int*   npos = (int*)  (ws + 12288);                              // 256 B
    float* acc  = (float*)(ws + 12544);                              // 16 B
    float* bto  = (float*)(ws + 12800);
    int*   bti  = (int*)  (ws + 12800 + (size_t)NB * NP * 4);
    float* cem  = (float*)(ws + 12800 + 2ULL * NB * NP * 4);

    hipMemsetAsync(d_ws, 0, 12560, stream);

    dim3 gm((NP + 1023) / 1024, NB);
    k_match <<<gm, 256, 0, stream>>>(arm_loc, priors, gt_boxes, bto, bti, best_key);
    k_force <<<1, 64, 0, stream>>>(best_key, bto, bti);
    k_loss  <<<4080, 256, 0, stream>>>(arm_loc, arm_conf, odm_loc, odm_conf, priors,
                                       gt_boxes, gt_labels, bto, bti, cem, npos, acc);
    k_select<<<NB, 256, 0, stream>>>(cem, npos, acc);
    k_final <<<1, 1, 0, stream>>>(acc, npos, out);
}

// Round 2
// 857.635 us; speedup vs baseline: 1.0965x; 1.0965x over previous
//
#include <hip/hip_runtime.h>
#include <math.h>

#define NB 64
#define NP 16320
#define NO 24
#define NC 81

// ---------------------------------------------------------------------------
// Workspace layout (bytes):
//   [0,           12288)   best_key  : u64[NB*NO]   (zeroed each launch)
//   [12288,       12544)   npos      : int[NB]      (zeroed)
//   [12544,       12560)   acc       : float[4]     (zeroed) 0=loss_l 1=ce_pos 2=ce_neg
//   [12800,       ...  )   bto       : float[NB*NP]
//   next                   bti       : int  [NB*NP]
//   next                   ce_mine   : float[NB*NP]
// ---------------------------------------------------------------------------

__device__ __forceinline__ float smooth_l1(float d) {
    float a = fabsf(d);
    return (a < 1.0f) ? 0.5f * a * a : a - 0.5f;
}

// Kernel 1: decode ARM boxes, IoU vs truths, per-prior best (bto/bti),
// per-truth best prior. Each thread owns 4 priors (block = 1024 priors);
// per-object cross-lane reduction uses a single packed u64 key
// (iou_bits<<32 | ~p; ties -> smallest p).
__global__ __launch_bounds__(256) void k_match(
    const float* __restrict__ arm_loc, const float* __restrict__ priors,
    const float* __restrict__ gt_boxes,
    float* __restrict__ bto, int* __restrict__ bti,
    unsigned long long* __restrict__ best_key)
{
    const int b     = blockIdx.y;
    const int tid   = threadIdx.x;
    const int pbase = blockIdx.x * 1024;

    __shared__ float tr[NO * 4];
    __shared__ unsigned long long sh_best[NO];
    if (tid < NO * 4) tr[tid] = gt_boxes[b * NO * 4 + tid];
    if (tid < NO)     sh_best[tid] = 0ULL;
    __syncthreads();

    float x0[4], y0[4], x1[4], y1[4], ab[4];
    bool  val[4];
    #pragma unroll
    for (int c = 0; c < 4; ++c) {
        const int p = pbase + c * 256 + tid;
        val[c] = (p < NP);
        const int pc = val[c] ? p : 0;
        const float4 l  = ((const float4*)arm_loc)[(size_t)b * NP + pc];
        const float4 pr = ((const float4*)priors)[pc];
        const float cx = pr.x + l.x * 0.1f * pr.z;
        const float cy = pr.y + l.y * 0.1f * pr.w;
        const float wx = pr.z * expf(l.z * 0.2f);
        const float wy = pr.w * expf(l.w * 0.2f);
        x0[c] = cx - wx * 0.5f; y0[c] = cy - wy * 0.5f;
        x1[c] = cx + wx * 0.5f; y1[c] = cy + wy * 0.5f;
        ab[c] = (x1[c] - x0[c]) * (y1[c] - y0[c]);
    }

    float best[4]  = {-1.0f, -1.0f, -1.0f, -1.0f};
    int   besto[4] = {0, 0, 0, 0};

    for (int o = 0; o < NO; ++o) {
        const float tx0 = tr[o * 4 + 0], ty0 = tr[o * 4 + 1];
        const float tx1 = tr[o * 4 + 2], ty1 = tr[o * 4 + 3];
        const float aa  = (tx1 - tx0) * (ty1 - ty0);

        unsigned long long key = 0ULL;
        #pragma unroll
        for (int c = 0; c < 4; ++c) {
            const float iw = fmaxf(fminf(tx1, x1[c]) - fmaxf(tx0, x0[c]), 0.0f);
            const float ih = fmaxf(fminf(ty1, y1[c]) - fmaxf(ty0, y0[c]), 0.0f);
            const float inter = iw * ih;
            const float iou = inter / (aa + ab[c] - inter);
            if (iou > best[c]) { best[c] = iou; besto[c] = o; }  // first occurrence
            const int p = pbase + c * 256 + tid;
            const unsigned long long kc =
                ((unsigned long long)__float_as_uint(iou) << 32) | (unsigned)~(unsigned)p;
            if (val[c] && kc > key) key = kc;
        }
        // 64-lane max of packed key
        #pragma unroll
        for (int d = 1; d < 64; d <<= 1) {
            const unsigned long long k2 = __shfl_xor(key, d, 64);
            if (k2 > key) key = k2;
        }
        if ((tid & 63) == 0) atomicMax(&sh_best[o], key);
    }

    #pragma unroll
    for (int c = 0; c < 4; ++c) {
        if (val[c]) {
            const size_t idx = (size_t)b * NP + (pbase + c * 256 + tid);
            bto[idx] = best[c];
            bti[idx] = besto[c];
        }
    }
    __syncthreads();
    if (tid < NO) atomicMax(&best_key[b * NO + tid], sh_best[tid]);
}

// Kernel 2: force-match best prior per truth (last write wins = np scatter).
__global__ void k_force(const unsigned long long* __restrict__ best_key,
                        float* __restrict__ bto, int* __restrict__ bti)
{
    const int b = blockIdx.x * blockDim.x + threadIdx.x;
    if (b >= NB) return;
    for (int o = 0; o < NO; ++o) {
        const unsigned long long k = best_key[b * NO + o];
        const unsigned p = ~(unsigned)(k & 0xffffffffULL);
        bto[(size_t)b * NP + p] = 2.0f;
        bti[(size_t)b * NP + p] = o;
    }
}

// Kernel 3: LDS-staged coalesced CE + SmoothL1.
// v3: two-pass LDS-resident logsumexp. NO register arrays (v2's x[21]+pre[6]
// spilled to scratch: WRITE_SIZE 6MB->326MB, VALUBusy 24%->5%). Pass 1 reads
// 21 elems from LDS into a 4-way fmaxf tree; a __syncthreads() memory fence
// stops the compiler from CSE-ing pass-2 LDS reads into pass-1 live ranges;
// pass 2 re-reads LDS and accumulates __expf into 4 independent accumulators
// (no serial rescale chain, no divergence).
__global__ __launch_bounds__(256) void k_loss(
    const float* __restrict__ arm_loc, const float* __restrict__ arm_conf,
    const float* __restrict__ odm_loc, const float* __restrict__ odm_conf,
    const float* __restrict__ priors,  const float* __restrict__ gt_boxes,
    const int*   __restrict__ gt_labels,
    const float* __restrict__ bto, const int* __restrict__ bti,
    float* __restrict__ ce_mine, int* __restrict__ npos, float* __restrict__ acc)
{
    const int tid = threadIdx.x;
    const size_t rbase = (size_t)blockIdx.x * 256;

    __shared__ float4 stage4[(64 * NC + 3) / 4];       // 5184 floats = 1296 float4
    __shared__ float  ce_sh[256];
    __shared__ int    conf_sh[256];
    float* stage = (float*)stage4;

    // Per-row target class.
    {
        const size_t row = rbase + tid;
        const int   bb = (int)(row / NP);
        const float ov = bto[row];
        const int   ti = bti[row];
        int ct = 0;
        if (!(ov < 0.5f)) ct = gt_labels[bb * NO + ti];
        conf_sh[tid] = ct;
    }
    __syncthreads();

    for (int s = 0; s < 4; ++s) {
        // Stage: 64 rows = 1296 float4, contiguous & 16B-aligned.
        const float4* src4 = (const float4*)(odm_conf + (rbase + 64 * (size_t)s) * NC);
        for (int i = tid; i < 1296; i += 256) stage4[i] = src4[i];
        __syncthreads();

        const int lr  = tid >> 2;          // local row 0..63
        const int q   = tid & 3;           // quarter 0..3
        const int tgt = conf_sh[64 * s + lr];
        const int j0  = q * 21;            // q<3: 21 elems; q==3: 18 valid
        const int jn  = (q == 3) ? 18 : 21;
        const float* rowp = stage + lr * NC;

        // Pass 1: branch-free max, 4 independent accumulators, LDS-resident.
        float m0 = -INFINITY, m1 = -INFINITY, m2 = -INFINITY, m3 = -INFINITY;
        #pragma unroll
        for (int jj = 0; jj < 21; jj += 4) {
            {            const float v = rowp[(jj     < jn) ? j0 + jj     : j0];
                         m0 = fmaxf(m0, (jj     < jn) ? v : -INFINITY); }
            if (jj + 1 < 21) { const float v = rowp[(jj + 1 < jn) ? j0 + jj + 1 : j0];
                         m1 = fmaxf(m1, (jj + 1 < jn) ? v : -INFINITY); }
            if (jj + 2 < 21) { const float v = rowp[(jj + 2 < jn) ? j0 + jj + 2 : j0];
                         m2 = fmaxf(m2, (jj + 2 < jn) ? v : -INFINITY); }
            if (jj + 3 < 21) { const float v = rowp[(jj + 3 < jn) ? j0 + jj + 3 : j0];
                         m3 = fmaxf(m3, (jj + 3 < jn) ? v : -INFINITY); }
        }
        float m = fmaxf(fmaxf(m0, m1), fmaxf(m2, m3));
        #pragma unroll
        for (int d = 1; d < 4; d <<= 1) m = fmaxf(m, __shfl_xor(m, d, 64));

        // Gather target logit (one LDS read; same addr for the 4 lanes of a row).
        const float gv = rowp[tgt];

        // Memory fence between passes: prevents CSE of pass-2 LDS reads into
        // pass-1 (which would recreate the 21-deep live range -> scratch spill).
        __syncthreads();

        // Pass 2: independent exps, 4 accumulators. Invalid lanes get
        // __expf(-INF - m) = 0 -- branch-free.
        float a0 = 0.0f, a1 = 0.0f, a2 = 0.0f, a3 = 0.0f;
        #pragma unroll
        for (int jj = 0; jj < 21; jj += 4) {
            {            const float v = rowp[(jj     < jn) ? j0 + jj     : j0];
                         a0 += __expf(((jj     < jn) ? v : -INFINITY) - m); }
            if (jj + 1 < 21) { const float v = rowp[(jj + 1 < jn) ? j0 + jj + 1 : j0];
                         a1 += __expf(((jj + 1 < jn) ? v : -INFINITY) - m); }
            if (jj + 2 < 21) { const float v = rowp[(jj + 2 < jn) ? j0 + jj + 2 : j0];
                         a2 += __expf(((jj + 2 < jn) ? v : -INFINITY) - m); }
            if (jj + 3 < 21) { const float v = rowp[(jj + 3 < jn) ? j0 + jj + 3 : j0];
                         a3 += __expf(((jj + 3 < jn) ? v : -INFINITY) - m); }
        }
        float sum = (a0 + a1) + (a2 + a3);
        #pragma unroll
        for (int d = 1; d < 4; d <<= 1) sum += __shfl_xor(sum, d, 64);

        if (q == 0) ce_sh[64 * s + lr] = (m + logf(sum)) - gv;
        __syncthreads();   // all reads of stage done before next phase's write
    }

    // Epilogue: per-thread row work (ocml-accurate math on threshold paths).
    float local_l = 0.0f, local_ce = 0.0f;
    int   local_n = 0;
    {
        const size_t row = rbase + tid;
        const int bb = (int)(row / NP);
        const int p  = (int)(row - (size_t)bb * NP);
        const int ct = conf_sh[tid];
        const float ce = ce_sh[tid];

        const float2 c = ((const float2*)arm_conf)[row];
        const float mm = fmaxf(c.x, c.y);
        const float e0 = expf(c.x - mm), e1 = expf(c.y - mm);
        const float score = e1 / (e0 + e1);
        const bool pos = (ct > 0) && (score > 0.01f);

        float cem = ce;
        if (pos) {
            cem      = 0.0f;
            local_ce = ce;
            local_n  = 1;
            const float4 l  = ((const float4*)arm_loc)[row];
            const float4 pr = ((const float4*)priors)[p];
            const float cx = pr.x + l.x * 0.1f * pr.z;
            const float cy = pr.y + l.y * 0.1f * pr.w;
            const float wx = pr.z * expf(l.z * 0.2f);
            const float wy = pr.w * expf(l.w * 0.2f);
            const float x0 = cx - wx * 0.5f, y0 = cy - wy * 0.5f;
            const float x1 = cx + wx * 0.5f, y1 = cy + wy * 0.5f;
            const float csx = (x0 + x1) * 0.5f, csy = (y0 + y1) * 0.5f;
            const float csw = x1 - x0,          csh = y1 - y0;
            const int ti = bti[row];
            const float4 mt = ((const float4*)gt_boxes)[bb * NO + ti];
            const float t0 = ((mt.x + mt.z) * 0.5f - csx) / (0.1f * csw);
            const float t1 = ((mt.y + mt.w) * 0.5f - csy) / (0.1f * csh);
            const float t2 = logf((mt.z - mt.x) / csw) / 0.2f;
            const float t3 = logf((mt.w - mt.y) / csh) / 0.2f;
            const float4 ol = ((const float4*)odm_loc)[row];
            local_l += smooth_l1(ol.x - t0);
            local_l += smooth_l1(ol.y - t1);
            local_l += smooth_l1(ol.z - t2);
            local_l += smooth_l1(ol.w - t3);
        }
        ce_mine[row] = cem;
    }

    // Block reduction (reuse stage LDS; protected by the final phase sync).
    float* sl = stage;
    float* sc = stage + 256;
    int*   sn = (int*)(stage + 512);
    sl[tid] = local_l; sc[tid] = local_ce; sn[tid] = local_n;
    __syncthreads();
    for (int st = 128; st > 0; st >>= 1) {
        if (tid < st) {
            sl[tid] += sl[tid + st];
            sc[tid] += sc[tid + st];
            sn[tid] += sn[tid + st];
        }
        __syncthreads();
    }
    if (tid == 0) {
        if (sl[0] != 0.0f) atomicAdd(&acc[0], sl[0]);
        if (sc[0] != 0.0f) atomicAdd(&acc[1], sc[0]);
    }
    // npos is per-batch; a block can span a batch boundary -> per-thread atomic
    // (only positives pay it; npos is small).
    {
        const size_t row = rbase + tid;
        const int bb = (int)(row / NP);
        if (local_n) atomicAdd(&npos[bb], 1);
    }
}

// Kernel 4: per-row radix select of k-th largest ce_mine.
// Per-wave privatized histograms (padded stride 257 to decouple banks)
// and a parallel suffix-scan instead of a serial 256-bin walk.
__global__ __launch_bounds__(256) void k_select(
    const float* __restrict__ ce_mine, const int* __restrict__ npos,
    float* __restrict__ acc)
{
    const int b   = blockIdx.x;
    const int tid = threadIdx.x;
    const int np  = npos[b];
    int k = 3 * np;
    if (k > NP - 1) k = NP - 1;
    if (k <= 0) return;

    const float4* row4 = (const float4*)(ce_mine + (size_t)b * NP);  // 4080 float4
    const int w = tid >> 6;

    __shared__ unsigned int hist[4][257];   // +1 pad: wave w starts at bank w
    __shared__ unsigned int scan[256];
    __shared__ unsigned int sh_prefix, sh_mask, sh_krem;
    if (tid == 0) { sh_prefix = 0u; sh_mask = 0u; sh_krem = (unsigned)k; }
    __syncthreads();

    for (int pass = 3; pass >= 0; --pass) {
        const unsigned mask   = sh_mask;
        const unsigned prefix = sh_prefix;
        const unsigned krem   = sh_krem;
        const int shift = pass * 8;

        hist[0][tid] = 0u; hist[1][tid] = 0u; hist[2][tid] = 0u; hist[3][tid] = 0u;
        __syncthreads();

        for (int i = tid; i < 4080; i += 256) {
            const float4 v = row4[i];
            const unsigned u0 = __float_as_uint(v.x);
            const unsigned u1 = __float_as_uint(v.y);
            const unsigned u2 = __float_as_uint(v.z);
            const unsigned u3 = __float_as_uint(v.w);
            if ((u0 & mask) == prefix) atomicAdd(&hist[w][(u0 >> shift) & 255u], 1u);
            if ((u1 & mask) == prefix) atomicAdd(&hist[w][(u1 >> shift) & 255u], 1u);
            if ((u2 & mask) == prefix) atomicAdd(&hist[w][(u2 >> shift) & 255u], 1u);
            if ((u3 & mask) == prefix) atomicAdd(&hist[w][(u3 >> shift) & 255u], 1u);
        }
        __syncthreads();

        const unsigned h = hist[0][tid] + hist[1][tid] + hist[2][tid] + hist[3][tid];
        scan[tid] = h;
        __syncthreads();
        // suffix-inclusive scan: scan[t] = sum_{j>=t} h[j]
        for (int off = 1; off < 256; off <<= 1) {
            const unsigned v = (tid + off < 256) ? scan[tid + off] : 0u;
            __syncthreads();
            scan[tid] += v;
            __syncthreads();
        }
        const unsigned sfx = scan[tid];
        if (sfx >= krem && (sfx - h) < krem) {   // unique threshold bin
            sh_prefix = prefix | ((unsigned)tid << shift);
            sh_mask   = mask | (255u << shift);
            sh_krem   = krem - (sfx - h);
        }
        __syncthreads();
    }

    const unsigned T = sh_prefix;   // exact bits of k-th largest
    float    lsum = 0.0f;
    unsigned lcnt = 0;
    for (int i = tid; i < 4080; i += 256) {
        const float4 v = row4[i];
        if (__float_as_uint(v.x) > T) { lsum += v.x; lcnt++; }
        if (__float_as_uint(v.y) > T) { lsum += v.y; lcnt++; }
        if (__float_as_uint(v.z) > T) { lsum += v.z; lcnt++; }
        if (__float_as_uint(v.w) > T) { lsum += v.w; lcnt++; }
    }
    __shared__ float    ssum[256];
    __shared__ unsigned scnt[256];
    ssum[tid] = lsum; scnt[tid] = lcnt;
    __syncthreads();
    for (int st = 128; st > 0; st >>= 1) {
        if (tid < st) { ssum[tid] += ssum[tid + st]; scnt[tid] += scnt[tid + st]; }
        __syncthreads();
    }
    if (tid == 0) {
        const float tf = __uint_as_float(T);
        const float contrib = ssum[0] + (float)(k - (int)scnt[0]) * tf;
        atomicAdd(&acc[2], contrib);
    }
}

// Kernel 5: finalize
__global__ void k_final(const float* __restrict__ acc, const int* __restrict__ npos,
                        float* __restrict__ out)
{
    if (threadIdx.x == 0 && blockIdx.x == 0) {
        int n = 0;
        for (int b = 0; b < NB; ++b) n += npos[b];
        const float N = (float)n;
        out[0] = acc[0] / N;
        out[1] = (acc[1] + acc[2]) / N;
    }
}

extern "C" void kernel_launch(void* const* d_in, const int* in_sizes, int n_in,
                              void* d_out, int out_size, void* d_ws, size_t ws_size,
                              hipStream_t stream)
{
    const float* arm_loc   = (const float*)d_in[0];
    const float* arm_conf  = (const float*)d_in[1];
    const float* odm_loc   = (const float*)d_in[2];
    const float* odm_conf  = (const float*)d_in[3];
    const float* priors    = (const float*)d_in[4];
    const float* gt_boxes  = (const float*)d_in[5];
    const int*   gt_labels = (const int*)d_in[6];
    float* out = (float*)d_out;

    char* ws = (char*)d_ws;
    unsigned long long* best_key = (unsigned long long*)ws;          // 12288 B
    int*   npos = (int*)  (ws + 12288);                              // 256 B
    float* acc  = (float*)(ws + 12544);                              // 16 B
    float* bto  = (float*)(ws + 12800);
    int*   bti  = (int*)  (ws + 12800 + (size_t)NB * NP * 4);
    float* cem  = (float*)(ws + 12800 + 2ULL * NB * NP * 4);

    hipMemsetAsync(d_ws, 0, 12560, stream);

    dim3 gm((NP + 1023) / 1024, NB);
    k_match <<<gm, 256, 0, stream>>>(arm_loc, priors, gt_boxes, bto, bti, best_key);
    k_force <<<1, 64, 0, stream>>>(best_key, bto, bti);
    k_loss  <<<4080, 256, 0, stream>>>(arm_loc, arm_conf, odm_loc, odm_conf, priors,
                                       gt_boxes, gt_labels, bto, bti, cem, npos, acc);
    k_select<<<NB, 256, 0, stream>>>(cem, npos, acc);
    k_final <<<1, 1, 0, stream>>>(acc, npos, out);
}